// Round 10
// baseline (184.045 us; speedup 1.0000x reference)
//
#include <hip/hip_runtime.h>

typedef unsigned short u16;
typedef unsigned int   u32;

typedef __attribute__((ext_vector_type(8))) short bf16x8;
typedef __attribute__((ext_vector_type(4))) short bf16x4;
typedef __attribute__((ext_vector_type(4))) float f32x4;

typedef const __attribute__((address_space(1))) u32 gq_t;   // global for async DMA
typedef __attribute__((address_space(3))) u32 lq_t;         // LDS for async DMA

// ---------- bf16 helpers (raw u16 carrier) ----------
__device__ __forceinline__ float b2f(u16 u) {
    union { u32 u; float f; } c; c.u = ((u32)u) << 16; return c.f;
}
__device__ __forceinline__ u16 f2b(float f) {
    union { float f; u32 u; } c; c.f = f;
    u32 r = c.u + 0x7fffu + ((c.u >> 16) & 1u);   // RNE
    return (u16)(r >> 16);
}
__device__ __forceinline__ u16 f2b_hu(float f) {  // half-up (magnitude): cheap
    union { float f; u32 u; } c; c.f = f;
    return (u16)((c.u + 0x8000u) >> 16);
}

// Q pre-scale: 1/sqrt(64) * log2(e), so softmax uses exp2 (bare v_exp_f32)
#define QSCALE 0.18033688011112042f

// ---------- fused prep: X f32->bf16 ; Wqkv^T ; Wproj^T (flat grid) ----------
__global__ __launch_bounds__(256) void prep(
    const float* __restrict__ X,    u16* __restrict__ Xb,
    const float* __restrict__ Wqkv, u16* __restrict__ WqkvT,
    const float* __restrict__ Wp,   u16* __restrict__ WprojT)
{
    __shared__ float t[32][33];
    const int bid = blockIdx.x, tid = threadIdx.x;
    if (bid < 2048) {                       // convert X (4.19M elems)
        const int i = (bid * 256 + tid) * 8;
        f32x4 a = *(const f32x4*)(X + i);
        f32x4 b = *(const f32x4*)(X + i + 4);
        union { bf16x8 v; u16 u[8]; } o;
        o.u[0] = f2b(a[0]); o.u[1] = f2b(a[1]); o.u[2] = f2b(a[2]); o.u[3] = f2b(a[3]);
        o.u[4] = f2b(b[0]); o.u[5] = f2b(b[1]); o.u[6] = f2b(b[2]); o.u[7] = f2b(b[3]);
        *(bf16x8*)(Xb + i) = o.v;
        return;
    }
    const float* in; u16* out; int N, bx, by;
    if (bid < 5120) { const int b2 = bid - 2048; in = Wqkv; out = WqkvT; N = 3072; bx = b2 % 96; by = b2 / 96; }
    else            { const int b3 = bid - 5120; in = Wp;   out = WprojT; N = 1024; bx = b3 & 31; by = b3 >> 5; }
    const int k0 = by * 32, n0 = bx * 32;
    const int kr = tid >> 3, nc = (tid & 7) * 4;
    f32x4 v = *(const f32x4*)(in + (size_t)(k0 + kr) * N + n0 + nc);
    t[kr][nc] = v[0]; t[kr][nc + 1] = v[1]; t[kr][nc + 2] = v[2]; t[kr][nc + 3] = v[3];
    __syncthreads();
    const int nr = tid >> 3, kc = (tid & 7) * 4;
    union { bf16x4 v; u16 a[4]; } o;
    o.a[0] = f2b(t[kc][nr]);     o.a[1] = f2b(t[kc + 1][nr]);
    o.a[2] = f2b(t[kc + 2][nr]); o.a[3] = f2b(t[kc + 3][nr]);
    *(bf16x4*)(out + (size_t)(n0 + nr) * 1024 + k0 + kc) = o.v;
}

// ---------- QKV GEMM, BK=64, XOR-swizzled LDS (verified 0-conflict pattern) ----
__global__ __launch_bounds__(256) void gemm128(
    const u16* __restrict__ A, const u16* __restrict__ WT,
    const float* __restrict__ bias, float* __restrict__ out,
    u16* __restrict__ Qb, u16* __restrict__ Kb, u16* __restrict__ Vt,
    int N, int K, int mode)
{
    __shared__ u16 As[128 * 64];
    __shared__ u16 Bs[128 * 64];
    const int tid  = threadIdx.x;
    const int m0   = blockIdx.y * 128, n0 = blockIdx.x * 128;
    const int wv   = tid >> 6, lane = tid & 63;
    const int wm   = (wv >> 1) * 64, wn = (wv & 1) * 64;
    const int l16  = lane & 15, quad = lane >> 4;

    const int srow = tid >> 3;                        // 0..31 (incl. wave bits)
    const int slog = ((tid & 7) ^ (srow & 7)) * 8;    // swizzled global source chunk
    const int rsw8 = l16 & 7;                         // read-side row swizzle key

    f32x4 acc[4][4];
    const f32x4 zero = {0.f, 0.f, 0.f, 0.f};
    #pragma unroll
    for (int i = 0; i < 4; i++)
        #pragma unroll
        for (int j = 0; j < 4; j++) acc[i][j] = zero;

    for (int k0 = 0; k0 < K; k0 += 64) {
        #pragma unroll
        for (int c = 0; c < 4; c++) {
            const u16* ag = A  + (size_t)(m0 + c * 32 + srow) * K + k0 + slog;
            const u16* bg = WT + (size_t)(n0 + c * 32 + srow) * K + k0 + slog;
            __builtin_amdgcn_global_load_lds((gq_t*)ag, (lq_t*)&As[c * 2048 + wv * 512], 16, 0, 0);
            __builtin_amdgcn_global_load_lds((gq_t*)bg, (lq_t*)&Bs[c * 2048 + wv * 512], 16, 0, 0);
        }
        __syncthreads();
        #pragma unroll
        for (int ks = 0; ks < 2; ks++) {
            const int ph = (((ks * 4 + quad) ^ rsw8) * 8);
            bf16x8 af[4], bfr[4];
            #pragma unroll
            for (int i = 0; i < 4; i++) {
                af[i]  = *(const bf16x8*)&As[(wm + i * 16 + l16) * 64 + ph];
                bfr[i] = *(const bf16x8*)&Bs[(wn + i * 16 + l16) * 64 + ph];
            }
            #pragma unroll
            for (int i = 0; i < 4; i++)
                #pragma unroll
                for (int j = 0; j < 4; j++)
                    acc[i][j] = __builtin_amdgcn_mfma_f32_16x16x32_bf16(af[i], bfr[j], acc[i][j], 0, 0, 0);
        }
        __syncthreads();
    }

    // C/D layout: col = l16, row = quad*4 + r
    #pragma unroll
    for (int j = 0; j < 4; j++) {
        const int nn = n0 + wn + j * 16 + l16;
        const float bvf = bias[nn];
        #pragma unroll
        for (int i = 0; i < 4; i++) {
            float o[4];
            #pragma unroll
            for (int r = 0; r < 4; r++) o[r] = acc[i][j][r] + bvf;
            const int mbase = m0 + wm + i * 16 + quad * 4;
            if (mode == 0) {
                #pragma unroll
                for (int r = 0; r < 4; r++)
                    out[(size_t)(mbase + r) * N + nn] = o[r];
            } else {
                const int part = nn >> 10, w = nn & 1023;
                const int h = w >> 6, d = w & 63;
                const int b = mbase >> 11, s = mbase & 2047;   // 4 consecutive s
                const size_t bh = (size_t)b * 16 + h;
                if (part == 2) {
                    union { bf16x4 v; u16 a[4]; } pk;
                    #pragma unroll
                    for (int r = 0; r < 4; r++) pk.a[r] = f2b_hu(o[r]);
                    *(bf16x4*)(Vt + (bh * 64 + d) * 2048 + s) = pk.v;
                } else {
                    u16* t = (part == 0) ? Qb : Kb;
                    const float scl = (part == 0) ? QSCALE : 1.0f;
                    #pragma unroll
                    for (int r = 0; r < 4; r++)
                        t[(bh * 2048 + s + r) * 64 + d] = f2b_hu(o[r] * scl);
                }
            }
        }
    }
}

// ---------- proj GEMM: 128(M)x64(N) tile, BK=32 -> 512 blocks (2/CU) ----------
__global__ __launch_bounds__(256) void gemm_proj(
    const u16* __restrict__ A, const u16* __restrict__ WT,
    const float* __restrict__ bias, float* __restrict__ out, int N, int K)
{
    __shared__ u16 As[128 * 32];
    __shared__ u16 Bs[64 * 32];
    const int tid  = threadIdx.x;
    const int m0   = blockIdx.y * 128, n0 = blockIdx.x * 64;
    const int wv   = tid >> 6, lane = tid & 63;
    const int wm   = (wv >> 1) * 64, wn = (wv & 1) * 32;
    const int l16  = lane & 15, quad = lane >> 4;

    const int sr = lane >> 2;
    const int sc = (((lane & 3) ^ ((lane >> 3) & 3)) * 8);
    const int rbase = wv * 16 + sr;
    const int rsw = ((l16 >> 1) & 3) * 8;

    f32x4 acc[4][2];
    const f32x4 zero = {0.f, 0.f, 0.f, 0.f};
    #pragma unroll
    for (int i = 0; i < 4; i++) { acc[i][0] = zero; acc[i][1] = zero; }

    for (int k0 = 0; k0 < K; k0 += 32) {
        #pragma unroll
        for (int c = 0; c < 2; c++) {
            const u16* ag = A + (size_t)(m0 + c * 64 + rbase) * K + k0 + sc;
            __builtin_amdgcn_global_load_lds((gq_t*)ag, (lq_t*)&As[(c * 64 + wv * 16) * 32], 16, 0, 0);
        }
        const u16* bg = WT + (size_t)(n0 + rbase) * K + k0 + sc;
        __builtin_amdgcn_global_load_lds((gq_t*)bg, (lq_t*)&Bs[(wv * 16) * 32], 16, 0, 0);
        __syncthreads();
        bf16x8 af[4], bfr[2];
        #pragma unroll
        for (int i = 0; i < 4; i++)
            af[i] = *(const bf16x8*)&As[(wm + i * 16 + l16) * 32 + ((quad * 8) ^ rsw)];
        #pragma unroll
        for (int j = 0; j < 2; j++)
            bfr[j] = *(const bf16x8*)&Bs[(wn + j * 16 + l16) * 32 + ((quad * 8) ^ rsw)];
        #pragma unroll
        for (int i = 0; i < 4; i++)
            #pragma unroll
            for (int j = 0; j < 2; j++)
                acc[i][j] = __builtin_amdgcn_mfma_f32_16x16x32_bf16(af[i], bfr[j], acc[i][j], 0, 0, 0);
        __syncthreads();
    }

    #pragma unroll
    for (int j = 0; j < 2; j++) {
        const int nn = n0 + wn + j * 16 + l16;
        const float bvf = bias[nn];
        #pragma unroll
        for (int i = 0; i < 4; i++) {
            const int mbase = m0 + wm + i * 16 + quad * 4;
            #pragma unroll
            for (int r = 0; r < 4; r++)
                out[(size_t)(mbase + r) * N + nn] = acc[i][j][r] + bvf;
        }
    }
}

// ---------- MFMA flash attention v6: DMA-staged, XOR-swizzled, double-buffered --
// 1024 blocks (4/CU, 66 tiles/CU uniform, bh pinned to XCD). K/V tiles DMA'd via
// global_load_lds into unpadded 64x64 LDS with phys_chunk = logical ^ (row&7)
// (the round-8-verified 0-conflict pattern). LDS = 2*16KB + 8KB p = 40KB ->
// 4 blocks/CU. exp2-domain softmax (Q pre-scaled by log2e/8). Row-sum via
// MFMA-with-ones. One barrier per tile.
__global__ __launch_bounds__(256, 4) void attn_mfma(
    const u16* __restrict__ Qb, const u16* __restrict__ Kb,
    const u16* __restrict__ Vt, u16* __restrict__ Aout)
{
    const int bx   = blockIdx.x;
    const int x    = bx & 511, half = bx >> 9;
    const int xcd  = x & 7, y = x >> 3;
    const int bh   = xcd * 4 + (y & 3);                 // 4 bh per XCD
    const int pidx = y >> 2;                            // 0..15
    const int chunk = half ? (31 - pidx) : pidx;        // pair-balanced
    const int q0   = chunk * 64;

    const int tid  = threadIdx.x;
    const int wave = tid >> 6, lane = tid & 63;
    const int l16  = lane & 15, quad = lane >> 4;
    const int qw   = q0 + wave * 16;
    const size_t kbase = (size_t)bh * 2048 * 64;        // Q,K: [s][d]
    const size_t vbase = (size_t)bh * 64 * 2048;        // Vt: [d][s]

    __shared__ __align__(16) u16 Ks[2][64 * 64];
    __shared__ __align__(16) u16 Vs[2][64 * 64];
    __shared__ __align__(16) u16 p_all[4][16 * 64];
    u16* p_lds = p_all[wave];                           // wave-private

    const u16* qp = Qb + kbase + (size_t)(qw + l16) * 64 + quad * 8;
    bf16x8 aq0 = *(const bf16x8*)qp;
    bf16x8 aq1 = *(const bf16x8*)(qp + 32);

    union { bf16x8 v; u16 a[8]; } onesu;
    #pragma unroll
    for (int j = 0; j < 8; j++) onesu.a[j] = 0x3F80;    // bf16 1.0
    const bf16x8 vones = onesu.v;

    f32x4 oacc[4], lacc;
    const f32x4 zero = {0.f, 0.f, 0.f, 0.f};
    #pragma unroll
    for (int t = 0; t < 4; t++) oacc[t] = zero;
    lacc = zero;

    // DMA staging geometry: wave w covers rows w*16..w*16+15, 2 instrs (8 rows each);
    // lane L -> row r0+(L>>3), phys chunk L&7, global logical chunk (L&7)^(L>>3).
    const int drow = lane >> 3;                         // 0..7
    const int dcol = ((lane & 7) ^ drow) * 8;           // swizzled source col (u16)
    const int r0a = wave * 16, r0b = wave * 16 + 8;

    #define STAGE(nb, kbt)                                                              \
    {                                                                                   \
        const u16* kga = Kb + kbase + (size_t)((kbt) + r0a + drow) * 64 + dcol;         \
        const u16* kgb = Kb + kbase + (size_t)((kbt) + r0b + drow) * 64 + dcol;         \
        const u16* vga = Vt + vbase + (size_t)(r0a + drow) * 2048 + (kbt) + dcol;       \
        const u16* vgb = Vt + vbase + (size_t)(r0b + drow) * 2048 + (kbt) + dcol;       \
        __builtin_amdgcn_global_load_lds((gq_t*)kga, (lq_t*)&Ks[nb][r0a * 64], 16, 0, 0);\
        __builtin_amdgcn_global_load_lds((gq_t*)kgb, (lq_t*)&Ks[nb][r0b * 64], 16, 0, 0);\
        __builtin_amdgcn_global_load_lds((gq_t*)vga, (lq_t*)&Vs[nb][r0a * 64], 16, 0, 0);\
        __builtin_amdgcn_global_load_lds((gq_t*)vgb, (lq_t*)&Vs[nb][r0b * 64], 16, 0, 0);\
    }

    STAGE(0, 0)
    __syncthreads();

    const int swk = l16 & 7;                            // read-side swizzle key
    for (int kt = 0; kt <= chunk; kt++) {
        const int kb = kt * 64, buf = kt & 1;
        if (kt < chunk) STAGE(buf ^ 1, kb + 64)         // prefetch next tile

        const u16* Kl = Ks[buf];
        const u16* Vl = Vs[buf];
        bf16x8 kk[8], vv[8];
        #pragma unroll
        for (int t = 0; t < 4; t++) {
            #pragma unroll
            for (int ks = 0; ks < 2; ks++) {
                const int ph = ((ks * 4 + quad) ^ swk) * 8;
                kk[2 * t + ks] = *(const bf16x8*)&Kl[(16 * t + l16) * 64 + ph];
                vv[2 * t + ks] = *(const bf16x8*)&Vl[(16 * t + l16) * 64 + ph];
            }
        }

        // ---- S = Q K^T (log2 domain) ----
        f32x4 sc[4];
        #pragma unroll
        for (int t = 0; t < 4; t++) {
            sc[t] = __builtin_amdgcn_mfma_f32_16x16x32_bf16(aq0, kk[2 * t],     zero,  0, 0, 0);
            sc[t] = __builtin_amdgcn_mfma_f32_16x16x32_bf16(aq1, kk[2 * t + 1], sc[t], 0, 0, 0);
        }

        // ---- p = 2^s, causal mask on diag tile; write P to swizzled wave-LDS ----
        const bool diag = (kt == chunk);
        #pragma unroll
        for (int r = 0; r < 4; r++) {
            const int row = quad * 4 + r;
            const int qi = qw + row;
            u16* pw = &p_lds[row * 64 + (l16 & 7)];
            const int rk = row & 7;
            #pragma unroll
            for (int t = 0; t < 4; t++) {
                float pv = exp2f(sc[t][r]);
                if (diag && (kb + 16 * t + l16 > qi)) pv = 0.f;
                pw[(((2 * t + (l16 >> 3)) ^ rk) * 8)] = f2b_hu(pv);
            }
        }

        __asm__ volatile("s_waitcnt lgkmcnt(0)");  // wave-private LDS roundtrip

        // ---- O += P V ; l += P·1 ----
        #pragma unroll
        for (int ks = 0; ks < 2; ks++) {
            bf16x8 ap = *(const bf16x8*)&p_lds[l16 * 64 + (((ks * 4 + quad) ^ swk) * 8)];
            #pragma unroll
            for (int t = 0; t < 4; t++)
                oacc[t] = __builtin_amdgcn_mfma_f32_16x16x32_bf16(ap, vv[2 * t + ks], oacc[t], 0, 0, 0);
            lacc = __builtin_amdgcn_mfma_f32_16x16x32_bf16(ap, vones, lacc, 0, 0, 0);
        }

        __syncthreads();   // drains DMA (vmcnt) + all LDS reads of buf done
    }

    // ---- epilogue: lane holds full row-sum in lacc[r] ----
    const int b = bh >> 4, h = bh & 15;
    #pragma unroll
    for (int r = 0; r < 4; r++) {
        const float inv = 1.0f / lacc[r];
        const int qi = qw + quad * 4 + r;
        u16* dst = Aout + (size_t)(b * 2048 + qi) * 1024 + h * 64 + l16;
        #pragma unroll
        for (int t = 0; t < 4; t++)
            dst[16 * t] = f2b_hu(oacc[t][r] * inv);
    }
    #undef STAGE
}

extern "C" void kernel_launch(void* const* d_in, const int* in_sizes, int n_in,
                              void* d_out, int out_size, void* d_ws, size_t ws_size,
                              hipStream_t stream)
{
    const float* X    = (const float*)d_in[0];   // [2,2048,1024] f32
    const float* Wqkv = (const float*)d_in[1];   // [1024,3072] f32
    const float* Bqkv = (const float*)d_in[2];   // [3072] f32
    const float* Wp   = (const float*)d_in[3];   // [1024,1024] f32
    const float* Bp   = (const float*)d_in[4];   // [1024] f32
    float* out = (float*)d_out;                  // [2,2048,1024] f32

    char* ws = (char*)d_ws;
    u16* WqkvT = (u16*)(ws);                     // 6.29 MB bf16
    u16* WprojT= (u16*)(ws + 6291456);           // 2.10 MB bf16
    u16* Qb    = (u16*)(ws + 8388608);           // [bh][s][d] 8.39 MB
    u16* Kb    = (u16*)(ws + 16777216);          // [bh][s][d]
    u16* Vt    = (u16*)(ws + 25165824);          // [bh][d][s]
    u16* Ab    = (u16*)(ws + 33554432);          // [b*s][h*64+d]
    u16* Xb    = (u16*)(ws + 41943040);          // [4096][1024] bf16 (total 50.3 MB)

    // fused prep: convert X + transpose both weights
    prep<<<dim3(6144), 256, 0, stream>>>(X, Xb, Wqkv, WqkvT, Wp, WprojT);

    // QKV: M=4096, N=3072, K=1024 -> Qb/Kb [bh][s][d], Vt [bh][d][s]
    gemm128<<<dim3(24, 32), 256, 0, stream>>>(Xb, WqkvT, Bqkv, nullptr,
                                              Qb, Kb, Vt, 3072, 1024, 1);
    // MFMA flash attention -> Ab merged heads, bf16
    attn_mfma<<<dim3(1024), 256, 0, stream>>>(Qb, Kb, Vt, Ab);
    // proj: M=4096, N=1024, K=1024 -> out f32 (512 blocks, 2/CU)
    gemm_proj<<<dim3(16, 32), 256, 0, stream>>>(Ab, WprojT, Bp, out, 1024, 1024);
}